// Round 4
// baseline (97.483 us; speedup 1.0000x reference)
//
#include <hip/hip_runtime.h>
#include <hip/hip_bf16.h>

// Per-token head-mixing attention, MI355X (gfx950).
// One wave (64 lanes) per token; tokens = B*S = 32768; 16 heads x 64 dim.
//
// R4 change: drop the ",4" from __launch_bounds__ — R3 showed the waves-per-EU
// annotation acted as an occupancy CAP (69% -> 35%), halving resident waves.
// Keep the R3 early-issue structure (all 40 global loads issued before any
// compute, pinned by sched_barrier(0); ~52 VGPR with counted-vmcnt register
// recycling). Target: ~8 waves/SIMD each with ~16 KB in flight -> HBM-bound.
//
// Phase 1: logits^T = K * Q^T via mfma_f32_16x16x32_bf16, Q/K split into
//          bf16 hi+lo (3 MFMAs per 32-d chunk) for ~fp32-accurate logits.
// Phase 2: wave-parallel softmax over 16 key-heads (lane-local 4 + xor16/32).
// Phase 3: out = W (16x32, j-padded) * V (32x64) via MFMA; W-frag assembled
//          in-register with 4 shfls. No LDS, no barriers.

typedef __attribute__((ext_vector_type(8))) short bf16x8;
typedef __attribute__((ext_vector_type(4))) float f32x4;

__device__ __forceinline__ unsigned short f2bf(float x) {
    unsigned int b = __float_as_uint(x);
    b += 0x7fffu + ((b >> 16) & 1u);   // round-to-nearest-even
    return (unsigned short)(b >> 16);
}
__device__ __forceinline__ float bf2f(unsigned short u) {
    return __uint_as_float(((unsigned int)u) << 16);
}

__global__ void __launch_bounds__(256)
headmix_attn_kernel(const float* __restrict__ Q, const float* __restrict__ K,
                    const float* __restrict__ V, float* __restrict__ O, int ntok)
{
    const int lane = (int)(threadIdx.x & 63u);
    const int wv   = (int)(threadIdx.x >> 6);
    const int tok  = (int)blockIdx.x * 4 + wv;
    if (tok >= ntok) return;

    const int r = lane & 15;   // A row (j) / B col (h) index
    const int g = lane >> 4;   // k-group 0..3

    const size_t base = (size_t)tok * 1024;
    const float* qt = Q + base;
    const float* kt = K + base;
    const float* vt = V + base;
    float*       ot = O + base;

    // =================== issue ALL global loads up front =====================
    f32x4 kvv[2][2], qvv[2][2];
#pragma unroll
    for (int mi = 0; mi < 2; ++mi) {
        const int off = r * 64 + mi * 32 + g * 8;   // 8 contiguous d's per lane
        kvv[mi][0] = *(const f32x4*)(kt + off);
        kvv[mi][1] = *(const f32x4*)(kt + off + 4);
        qvv[mi][0] = *(const f32x4*)(qt + off);
        qvv[mi][1] = *(const f32x4*)(qt + off + 4);
    }
    // V in B-frag pattern: lane needs V[8g'+i][dt*16+r] for g'=g&1 (g>=2 lanes
    // duplicate g&1's addresses -> dedup'd in cache; their frag is zeroed later)
    float vraw[4][8];
#pragma unroll
    for (int dt = 0; dt < 4; ++dt) {
        const float* vp = vt + (8 * (g & 1)) * 64 + dt * 16 + r;
#pragma unroll
        for (int i = 0; i < 8; ++i)
            vraw[dt][i] = vp[i * 64];
    }

    // Pin the schedule: loads above may not sink below this point.
    __builtin_amdgcn_sched_barrier(0);

    // ---------------- Phase 1: logits^T[j][h] = sum_d K[j][d] * Q[h][d] ------
    f32x4 acc = {0.f, 0.f, 0.f, 0.f};
#pragma unroll
    for (int mi = 0; mi < 2; ++mi) {
        bf16x8 kh, kl, qh, ql;
#pragma unroll
        for (int half = 0; half < 2; ++half) {
#pragma unroll
            for (int i = 0; i < 4; ++i) {
                float kf = kvv[mi][half][i];
                float qf = qvv[mi][half][i];
                unsigned short khi = f2bf(kf);
                unsigned short qhi = f2bf(qf);
                kh[half * 4 + i] = (short)khi;
                qh[half * 4 + i] = (short)qhi;
                kl[half * 4 + i] = (short)f2bf(kf - bf2f(khi));
                ql[half * 4 + i] = (short)f2bf(qf - bf2f(qhi));
            }
        }
        // (kh+kl)*(qh+ql) ~= kh*qh + kl*qh + kh*ql  (kl*ql ~ 2^-18, dropped)
        acc = __builtin_amdgcn_mfma_f32_16x16x32_bf16(kh, qh, acc, 0, 0, 0);
        acc = __builtin_amdgcn_mfma_f32_16x16x32_bf16(kl, qh, acc, 0, 0, 0);
        acc = __builtin_amdgcn_mfma_f32_16x16x32_bf16(kh, ql, acc, 0, 0, 0);
    }
    // D layout: col = h = lane&15, rows j = 4g + i

    // ---------------- Phase 2: softmax over j (16) for column h=r ------------
    // 1/sqrt(64) = 0.125 folded into the exp argument (exact pow2 scale).
    float m = fmaxf(fmaxf(acc[0], acc[1]), fmaxf(acc[2], acc[3]));
    m = fmaxf(m, __shfl_xor(m, 16));
    m = fmaxf(m, __shfl_xor(m, 32));
    float p0 = __expf(0.125f * (acc[0] - m));
    float p1 = __expf(0.125f * (acc[1] - m));
    float p2 = __expf(0.125f * (acc[2] - m));
    float p3 = __expf(0.125f * (acc[3] - m));
    float s = p0 + p1 + p2 + p3;
    s += __shfl_xor(s, 16);
    s += __shfl_xor(s, 32);
    const float inv = 1.0f / s;
    p0 *= inv; p1 *= inv; p2 *= inv; p3 *= inv;

    // lane holds W[h=r][j=4g+i]; pack to bf16 pairs
    unsigned int w01 = (unsigned int)f2bf(p0) | ((unsigned int)f2bf(p1) << 16);
    unsigned int w23 = (unsigned int)f2bf(p2) | ((unsigned int)f2bf(p3) << 16);

    // ---------------- Phase 3: out = W (16x32, j-padded) * V (32x64) ---------
    // A-frag: lane row h=r, k-elems j = 8g..8g+7 -> gather from lane groups
    // 2g and 2g+1 (same col r). g>=2 => j>=16 => zero padding.
    const int src0 = (r + 32 * g) & 63;
    const int src1 = (r + 32 * g + 16) & 63;
    unsigned int a0 = (unsigned int)__shfl((int)w01, src0);
    unsigned int a1 = (unsigned int)__shfl((int)w23, src0);
    unsigned int a2 = (unsigned int)__shfl((int)w01, src1);
    unsigned int a3 = (unsigned int)__shfl((int)w23, src1);
    if (g >= 2) { a0 = 0u; a1 = 0u; a2 = 0u; a3 = 0u; }

    union { bf16x8 v; unsigned int u[4]; } wf;
    wf.u[0] = a0; wf.u[1] = a1; wf.u[2] = a2; wf.u[3] = a3;

    const f32x4 zero = {0.f, 0.f, 0.f, 0.f};
#pragma unroll
    for (int dt = 0; dt < 4; ++dt) {
        union { bf16x8 v; unsigned int u[4]; } vf;
#pragma unroll
        for (int i = 0; i < 4; ++i) {
            unsigned int lo = (unsigned int)f2bf(vraw[dt][2 * i]);
            unsigned int hi = (unsigned int)f2bf(vraw[dt][2 * i + 1]);
            vf.u[i] = (g < 2) ? (lo | (hi << 16)) : 0u;
        }
        f32x4 o = __builtin_amdgcn_mfma_f32_16x16x32_bf16(wf.v, vf.v, zero, 0, 0, 0);
        // D: row = h = 4g+i, col = d = dt*16 + r
        float* op = ot + (4 * g) * 64 + dt * 16 + r;
#pragma unroll
        for (int i = 0; i < 4; ++i) op[i * 64] = o[i];
    }
}

extern "C" void kernel_launch(void* const* d_in, const int* in_sizes, int n_in,
                              void* d_out, int out_size, void* d_ws, size_t ws_size,
                              hipStream_t stream) {
    const float* q = (const float*)d_in[0];
    const float* k = (const float*)d_in[1];
    const float* v = (const float*)d_in[2];
    float* o = (float*)d_out;
    const int ntok = in_sizes[0] / 1024;          // B*S = 32768
    const int blocks = (ntok + 3) / 4;            // 4 tokens (waves) per block
    hipLaunchKernelGGL(headmix_attn_kernel, dim3(blocks), dim3(256), 0, stream,
                       q, k, v, o, ntok);
}

// Round 5
// 97.176 us; speedup vs baseline: 1.0032x; 1.0032x over previous
//
#include <hip/hip_runtime.h>
#include <hip/hip_bf16.h>

// Per-token head-mixing attention, MI355X (gfx950).
// One wave (64 lanes) per token; tokens = B*S = 32768; 16 heads x 64 dim.
//
// R5 change: V is staged global->LDS via __builtin_amdgcn_global_load_lds
// (4 x 16B/lane, linear dest — the legal wave-uniform-base pattern). This
// decouples in-flight bytes from VGPR liveness: R3/R4 showed the allocator
// chops register-held load bursts (waitcnt inside the load block) to stay at
// ~52 VGPRs, capping memory-level parallelism at ~7.5 KB/wave. Now each wave
// keeps K+Q (32 regs) + V (LDS, vmcnt-tracked, zero regs) = 12 KB in flight
// in one latency exposure, while staying under the 64-VGPR / 8-waves-per-SIMD
// occupancy budget. V frags are then read back with ds_read_b32 in the MFMA
// B-frag pattern (2-way bank aliasing = free). No __syncthreads anywhere
// (each wave touches only its own LDS quarter).
//
// Phase 1: logits^T = K * Q^T via mfma_f32_16x16x32_bf16, Q/K split into
//          bf16 hi+lo (3 MFMAs per 32-d chunk) for ~fp32-accurate logits.
// Phase 2: wave-parallel softmax over 16 key-heads (lane-local 4 + xor16/32).
// Phase 3: out = W (16x32, j-padded) * V (32x64) via MFMA; W-frag assembled
//          in-register with 4 shfls.

typedef __attribute__((ext_vector_type(8))) short bf16x8;
typedef __attribute__((ext_vector_type(4))) float f32x4;

#define AS1 __attribute__((address_space(1)))
#define AS3 __attribute__((address_space(3)))

__device__ __forceinline__ unsigned short f2bf(float x) {
    unsigned int b = __float_as_uint(x);
    b += 0x7fffu + ((b >> 16) & 1u);   // round-to-nearest-even
    return (unsigned short)(b >> 16);
}
__device__ __forceinline__ float bf2f(unsigned short u) {
    return __uint_as_float(((unsigned int)u) << 16);
}

__global__ void __launch_bounds__(256)
headmix_attn_kernel(const float* __restrict__ Q, const float* __restrict__ K,
                    const float* __restrict__ V, float* __restrict__ O, int ntok)
{
    __shared__ float vbuf[4][1024];   // 4 KB per wave, 16 KB per block

    const int lane = (int)(threadIdx.x & 63u);
    const int wv   = (int)(threadIdx.x >> 6);
    const int tok  = (int)blockIdx.x * 4 + wv;
    if (tok >= ntok) return;          // never taken at 32768 tokens

    const int r = lane & 15;   // A row (j) / B col (h) index
    const int g = lane >> 4;   // k-group 0..3

    const size_t base = (size_t)tok * 1024;
    const float* qt = Q + base;
    const float* kt = K + base;
    const float* vt = V + base;
    float*       ot = O + base;

    // =================== issue ALL global loads up front =====================
    // K/Q: 8 x dwordx4 into registers (32 VGPRs live).
    f32x4 kvv[2][2], qvv[2][2];
#pragma unroll
    for (int mi = 0; mi < 2; ++mi) {
        const int off = r * 64 + mi * 32 + g * 8;   // 8 contiguous d's per lane
        kvv[mi][0] = *(const f32x4*)(kt + off);
        kvv[mi][1] = *(const f32x4*)(kt + off + 4);
        qvv[mi][0] = *(const f32x4*)(qt + off);
        qvv[mi][1] = *(const f32x4*)(qt + off + 4);
    }
    // V: 4 KB contiguous token slab, global -> LDS direct (no VGPR liveness).
    // Lane i's 16 B land at ldsbase + i*16 — linear copy of vt[0..1023].
    float* lwave = vbuf[wv];
#pragma unroll
    for (int c = 0; c < 4; ++c) {
        const float* gsrc = vt + c * 256 + lane * 4;
        __builtin_amdgcn_global_load_lds((const AS1 void*)gsrc,
                                         (AS3 void*)(lwave + c * 256),
                                         16, 0, 0);
    }

    // Pin the schedule: loads above may not sink below this point.
    __builtin_amdgcn_sched_barrier(0);

    // ---------------- Phase 1: logits^T[j][h] = sum_d K[j][d] * Q[h][d] ------
    f32x4 acc = {0.f, 0.f, 0.f, 0.f};
#pragma unroll
    for (int mi = 0; mi < 2; ++mi) {
        bf16x8 kh, kl, qh, ql;
#pragma unroll
        for (int half = 0; half < 2; ++half) {
#pragma unroll
            for (int i = 0; i < 4; ++i) {
                float kf = kvv[mi][half][i];
                float qf = qvv[mi][half][i];
                unsigned short khi = f2bf(kf);
                unsigned short qhi = f2bf(qf);
                kh[half * 4 + i] = (short)khi;
                qh[half * 4 + i] = (short)qhi;
                kl[half * 4 + i] = (short)f2bf(kf - bf2f(khi));
                ql[half * 4 + i] = (short)f2bf(qf - bf2f(qhi));
            }
        }
        // (kh+kl)*(qh+ql) ~= kh*qh + kl*qh + kh*ql  (kl*ql ~ 2^-18, dropped)
        acc = __builtin_amdgcn_mfma_f32_16x16x32_bf16(kh, qh, acc, 0, 0, 0);
        acc = __builtin_amdgcn_mfma_f32_16x16x32_bf16(kl, qh, acc, 0, 0, 0);
        acc = __builtin_amdgcn_mfma_f32_16x16x32_bf16(kh, ql, acc, 0, 0, 0);
    }
    // D layout: col = h = lane&15, rows j = 4g + i

    // ---------------- Phase 2: softmax over j (16) for column h=r ------------
    // 1/sqrt(64) = 0.125 folded into the exp argument (exact pow2 scale).
    float m = fmaxf(fmaxf(acc[0], acc[1]), fmaxf(acc[2], acc[3]));
    m = fmaxf(m, __shfl_xor(m, 16));
    m = fmaxf(m, __shfl_xor(m, 32));
    float p0 = __expf(0.125f * (acc[0] - m));
    float p1 = __expf(0.125f * (acc[1] - m));
    float p2 = __expf(0.125f * (acc[2] - m));
    float p3 = __expf(0.125f * (acc[3] - m));
    float s = p0 + p1 + p2 + p3;
    s += __shfl_xor(s, 16);
    s += __shfl_xor(s, 32);
    const float inv = 1.0f / s;
    p0 *= inv; p1 *= inv; p2 *= inv; p3 *= inv;

    // lane holds W[h=r][j=4g+i]; pack to bf16 pairs
    unsigned int w01 = (unsigned int)f2bf(p0) | ((unsigned int)f2bf(p1) << 16);
    unsigned int w23 = (unsigned int)f2bf(p2) | ((unsigned int)f2bf(p3) << 16);

    // ---------------- Phase 3: out = W (16x32, j-padded) * V (32x64) ---------
    // A-frag: lane row h=r, k-elems j = 8g..8g+7 -> gather from lane groups
    // 2g and 2g+1 (same col r). g>=2 => j>=16 => zero padding.
    const int src0 = (r + 32 * g) & 63;
    const int src1 = (r + 32 * g + 16) & 63;
    unsigned int a0 = (unsigned int)__shfl((int)w01, src0);
    unsigned int a1 = (unsigned int)__shfl((int)w23, src0);
    unsigned int a2 = (unsigned int)__shfl((int)w01, src1);
    unsigned int a3 = (unsigned int)__shfl((int)w23, src1);
    if (g >= 2) { a0 = 0u; a1 = 0u; a2 = 0u; a3 = 0u; }

    union { bf16x8 v; unsigned int u[4]; } wf;
    wf.u[0] = a0; wf.u[1] = a1; wf.u[2] = a2; wf.u[3] = a3;

    // Ensure the V LDS slab has landed (vmcnt covers global_load_lds).
    asm volatile("s_waitcnt vmcnt(0)" ::: "memory");

    const int gp = g & 1;   // g>=2 lanes mirror g&1 (frag zeroed below)
    const f32x4 zero = {0.f, 0.f, 0.f, 0.f};
#pragma unroll
    for (int dt = 0; dt < 4; ++dt) {
        // B-frag: lane col = dt*16+r, k-elems j = 8*gp + i; zero for g>=2.
        // LDS bank = (dt*16 + r) % 32 -> 16 banks x 2 rows = 2-way (free).
        union { bf16x8 v; unsigned int u[4]; } vf;
#pragma unroll
        for (int i = 0; i < 4; ++i) {
            float v0 = lwave[(8 * gp + 2 * i)     * 64 + dt * 16 + r];
            float v1 = lwave[(8 * gp + 2 * i + 1) * 64 + dt * 16 + r];
            unsigned int lo = (unsigned int)f2bf(v0);
            unsigned int hi = (unsigned int)f2bf(v1);
            vf.u[i] = (g < 2) ? (lo | (hi << 16)) : 0u;
        }
        f32x4 o = __builtin_amdgcn_mfma_f32_16x16x32_bf16(wf.v, vf.v, zero, 0, 0, 0);
        // D: row = h = 4g+i, col = d = dt*16 + r
        float* op = ot + (4 * g) * 64 + dt * 16 + r;
#pragma unroll
        for (int i = 0; i < 4; ++i) op[i * 64] = o[i];
    }
}

extern "C" void kernel_launch(void* const* d_in, const int* in_sizes, int n_in,
                              void* d_out, int out_size, void* d_ws, size_t ws_size,
                              hipStream_t stream) {
    const float* q = (const float*)d_in[0];
    const float* k = (const float*)d_in[1];
    const float* v = (const float*)d_in[2];
    float* o = (float*)d_out;
    const int ntok = in_sizes[0] / 1024;          // B*S = 32768
    const int blocks = (ntok + 3) / 4;            // 4 tokens (waves) per block
    hipLaunchKernelGGL(headmix_attn_kernel, dim3(blocks), dim3(256), 0, stream,
                       q, k, v, o, ntok);
}